// Round 1
// 366.413 us; speedup vs baseline: 1.0164x; 1.0164x over previous
//
#include <hip/hip_runtime.h>
#include <math.h>

#define HDIM 768
#define HIDD 512
#define NTOK 16384
#define NT 20
#define CHUNKS 128
#define CLEN 128

typedef unsigned short ushort_t;
typedef __attribute__((ext_vector_type(8))) short bf16x8;
typedef __attribute__((ext_vector_type(4))) float f32x4;

__device__ __forceinline__ float sigm(float x){ return 1.0f/(1.0f+expf(-x)); }

__device__ __forceinline__ ushort_t f2bf(float f){
    unsigned int u = __float_as_uint(f);
    unsigned int r = (u + 0x7fffu + ((u >> 16) & 1u)) >> 16;
    return (ushort_t)r;
}
__device__ __forceinline__ float bf2f(ushort_t b){
    return __uint_as_float(((unsigned int)b) << 16);
}

#define GLD16(gp, lp) __builtin_amdgcn_global_load_lds( \
    (const __attribute__((address_space(1))) void*)(gp), \
    (__attribute__((address_space(3))) void*)(lp), 16, 0, 0)

// ---------------------------------------------------------------------------
// conv: blocks [0,1152) pack B (w_ih f/b gates i,g,o) -> Bh/Bl (1536x768);
// blocks [1152,13440) split x rows 1..16384 -> Ah/Al (16384x768).
// ---------------------------------------------------------------------------
__global__ __launch_bounds__(256) void conv_kernel(
    const float* __restrict__ x,
    const float* __restrict__ wf, const float* __restrict__ wb,
    ushort_t* __restrict__ Ah, ushort_t* __restrict__ Al,
    ushort_t* __restrict__ Bh, ushort_t* __restrict__ Bl)
{
    const int bid = blockIdx.x;
    if (bid < 1152){
        int t = bid*256 + threadIdx.x;                 // 1536*192
        int n = t / 192, c4 = (t - n*192)*4;
        int dir = n / 768, nr = n - dir*768;
        int gate = nr >> 8, j = nr & 255;
        int wrow = j + ((gate==0)?0:((gate==1)?512:768));
        const float* src = dir ? wb : wf;
        const float4 v = *(const float4*)(src + (size_t)wrow*HDIM + c4);
        float f[4] = {v.x, v.y, v.z, v.w};
        ushort_t h[4], l[4];
        #pragma unroll
        for (int i=0;i<4;++i){
            h[i] = f2bf(f[i]);
            l[i] = f2bf(f[i] - bf2f(h[i]));
        }
        *(ushort4*)(Bh + (size_t)n*HDIM + c4) = make_ushort4(h[0],h[1],h[2],h[3]);
        *(ushort4*)(Bl + (size_t)n*HDIM + c4) = make_ushort4(l[0],l[1],l[2],l[3]);
    } else {
        int t = (bid-1152)*256 + threadIdx.x;          // 16384*192
        int row = t / 192, c4 = (t - row*192)*4;
        const float4 v = *(const float4*)(x + (size_t)(row+1)*HDIM + c4);
        float f[4] = {v.x, v.y, v.z, v.w};
        ushort_t h[4], l[4];
        #pragma unroll
        for (int i=0;i<4;++i){
            h[i] = f2bf(f[i]);
            l[i] = f2bf(f[i] - bf2f(h[i]));
        }
        *(ushort4*)(Ah + (size_t)row*HDIM + c4) = make_ushort4(h[0],h[1],h[2],h[3]);
        *(ushort4*)(Al + (size_t)row*HDIM + c4) = make_ushort4(l[0],l[1],l[2],l[3]);
    }
}

// ---------------------------------------------------------------------------
// Split-bf16 MFMA GEMM, 3 gates, + activation + partial feats.
//
// R9 restructure (T3+T4+T5): the old 1-barrier-per-kt loop drained
// vmcnt(0) at every __syncthreads (m97-structure: MfmaUtil capped ~37%).
// New schedule: 3 phases per kt (one per gate cluster), raw s_barrier +
// COUNTED vmcnt so prefetch batches stay in flight across ~3 barriers:
//   batches per kt: b0 = A(4)+Bg0(2)=6, b1 = Bg1(2), b2 = Bg2(2)
//   issued during tile kt's phases for tile kt+1.
//   steady waits: P0 needs b0 -> newer b1+b2      = 4 -> vmcnt(4)
//                 P1 needs b1 -> newer b2+b0'     = 8 -> vmcnt(8)
//                 P2 needs b2 -> newer b0'+b1'    = 8 -> vmcnt(8)
//   kt=23 peeled (no issues): exact waits 4/2/0.
// Hazards: region's last ds_read completes at its phase lgkmcnt(0),
// >=3 barriers before that region's next GLD16 write; per-wave counted
// vmcnt + barrier => all waves' batch landed before any consumer read.
// Per-acc MFMA sequence identical to R8 -> bit-identical gates/feats.
// 80 KB LDS, 2 blocks/CU unchanged.
// ---------------------------------------------------------------------------
#define VMCNT(n) asm volatile("s_waitcnt vmcnt(" #n ")" ::: "memory")
#define LGKM0()  do{ asm volatile("s_waitcnt lgkmcnt(0)" ::: "memory"); \
                     __builtin_amdgcn_sched_barrier(0); }while(0)

#define MFMA_CLUSTER(g, BH0, BL0, BH1, BL1) do{                               \
    _Pragma("unroll")                                                         \
    for (int fm=0; fm<4; ++fm){                                               \
        acc[g][fm][0] = __builtin_amdgcn_mfma_f32_16x16x32_bf16(afh[fm], BH0, \
                            acc[g][fm][0], 0, 0, 0);                          \
        acc[g][fm][0] = __builtin_amdgcn_mfma_f32_16x16x32_bf16(afl[fm], BH0, \
                            acc[g][fm][0], 0, 0, 0);                          \
        acc[g][fm][0] = __builtin_amdgcn_mfma_f32_16x16x32_bf16(afh[fm], BL0, \
                            acc[g][fm][0], 0, 0, 0);                          \
    }                                                                         \
    _Pragma("unroll")                                                         \
    for (int fm=0; fm<4; ++fm){                                               \
        acc[g][fm][1] = __builtin_amdgcn_mfma_f32_16x16x32_bf16(afh[fm], BH1, \
                            acc[g][fm][1], 0, 0, 0);                          \
        acc[g][fm][1] = __builtin_amdgcn_mfma_f32_16x16x32_bf16(afl[fm], BH1, \
                            acc[g][fm][1], 0, 0, 0);                          \
        acc[g][fm][1] = __builtin_amdgcn_mfma_f32_16x16x32_bf16(afh[fm], BL1, \
                            acc[g][fm][1], 0, 0, 0);                          \
    }                                                                         \
}while(0)

#define READ_A(ab) do{ _Pragma("unroll") for (int f=0; f<4; ++f){             \
    afh[f] = *(const bf16x8*)((ab) + aoffB[f]);                               \
    afl[f] = *(const bf16x8*)((ab) + 8192 + aoffB[f]); } }while(0)

__global__ __launch_bounds__(256, 2) void gemm_fused(
    const ushort_t* __restrict__ Ah, const ushort_t* __restrict__ Al,
    const ushort_t* __restrict__ Bh, const ushort_t* __restrict__ Bl,
    const float* __restrict__ bihf, const float* __restrict__ bhhf,
    const float* __restrict__ bihb, const float* __restrict__ bhhb,
    const float* __restrict__ wtag, float* __restrict__ featsp)
{
    __shared__ __align__(16) char smem[81920];
    // A: buf b at b*16384: Ah rows0-63 @0, rows64-127 @4096, Al @8192/@12288
    // B: 32768 + b*24576 + g*8192 (h @0, l @4096)
    float* hbuf = (float*)smem;                          // epilogue 64x65 f32
    float* wts  = (float*)(smem + 16640);                // epilogue 20x64 f32

    const int tid = threadIdx.x;
    const int bx = blockIdx.x;
    const int xcd = bx & 7, g3 = bx >> 3;
    const int q = g3 & 7, mt = (g3 >> 3)*8 + xcd;        // 8 q-blocks share XCD
    const int dir = q >> 2, j0 = (q & 3)*64;
    const int row0 = mt*128;
    const float* __restrict__ bih = dir ? bihb : bihf;
    const float* __restrict__ bhh = dir ? bhhb : bhhf;

    const int lane = tid & 63, wv = tid >> 6;
    const int wm = wv >> 1, wn = wv & 1;
    const int lm = lane & 15, lq = lane >> 4;
    const int wbB = (tid & 192) * 16;                    // wave-uniform byte base

    // ---- staging decode: chunk C=tid -> (row, k8) under pair swizzle ------
    const int P_ = tid >> 3, s_ = tid & 7;
    const int q_ = s_ ^ (P_ & 7);
    const int mA = (P_ << 1) | (q_ >> 2);                // row 0..63 in group
    const int k8s = q_ & 3;
    const size_t aoff0 = (size_t)(row0 + mA)*HDIM + k8s*8;        // rows 0-63
    const size_t aoff1 = (size_t)(row0 + 64 + mA)*HDIM + k8s*8;   // rows 64-127
    size_t bOff[3];
    #pragma unroll
    for (int g=0; g<3; ++g)
        bOff[g] = (size_t)(dir*768 + g*256 + j0 + mA)*HDIM + k8s*8;

    // ---- fragment ds_read byte offsets ------------------------------------
    int aoffB[4], boffB[2];
    #pragma unroll
    for (int f=0; f<4; ++f){
        int m = wm*64 + f*16 + lm;                       // 0..127
        int rg = m >> 6, r = m & 63;
        aoffB[f] = rg*4096 + ((r>>1)*8 + ((((r&1)<<2)|lq) ^ ((r>>1)&7)))*16;
    }
    #pragma unroll
    for (int f=0; f<2; ++f){
        int n = wn*32 + f*16 + lm;                       // 0..63
        boffB[f] = ((n>>1)*8 + ((((n&1)<<2)|lq) ^ ((n>>1)&7)))*16;
    }

    int jcol[2];
    #pragma unroll
    for (int f=0; f<2; ++f) jcol[f] = j0 + wn*32 + f*16 + lm;

    f32x4 acc[3][4][2];                                  // [gate][fm][fn]
    #pragma unroll
    for (int g=0; g<3; ++g)
        #pragma unroll
        for (int fm=0; fm<4; ++fm)
            #pragma unroll
            for (int fn=0; fn<2; ++fn)
                acc[g][fm][fn] = (f32x4){0.f,0.f,0.f,0.f};

    bf16x8 afh[4], afl[4];                               // persist across phases

    // ---- prologue: issue kt=0 batches in order b0(A+g0), b1(g1), b2(g2) ---
    {
        char* ab = smem;
        char* bb = smem + 32768;
        GLD16(Ah + aoff0, ab + wbB);
        GLD16(Ah + aoff1, ab + 4096 + wbB);
        GLD16(Al + aoff0, ab + 8192 + wbB);
        GLD16(Al + aoff1, ab + 12288 + wbB);
        GLD16(Bh + bOff[0], bb + wbB);
        GLD16(Bl + bOff[0], bb + 4096 + wbB);
        GLD16(Bh + bOff[1], bb + 8192 + wbB);
        GLD16(Bl + bOff[1], bb + 12288 + wbB);
        GLD16(Bh + bOff[2], bb + 16384 + wbB);
        GLD16(Bl + bOff[2], bb + 20480 + wbB);
    }

    #pragma unroll 1
    for (int kt=0; kt<23; ++kt){
        const char* ab = smem + (kt&1)*16384;
        const char* bb = smem + 32768 + (kt&1)*24576;
        char* abn = smem + ((kt+1)&1)*16384;
        char* bbn = smem + 32768 + ((kt+1)&1)*24576;
        const int k0n = (kt+1)*32;

        // -------- phase 0: A + gate 0; issue b0' --------
        VMCNT(4);
        __builtin_amdgcn_s_barrier();
        READ_A(ab);
        {
            bf16x8 bh0 = *(const bf16x8*)(bb + boffB[0]);
            bf16x8 bl0 = *(const bf16x8*)(bb + 4096 + boffB[0]);
            bf16x8 bh1 = *(const bf16x8*)(bb + boffB[1]);
            bf16x8 bl1 = *(const bf16x8*)(bb + 4096 + boffB[1]);
            GLD16(Ah + aoff0 + k0n, abn + wbB);
            GLD16(Ah + aoff1 + k0n, abn + 4096 + wbB);
            GLD16(Al + aoff0 + k0n, abn + 8192 + wbB);
            GLD16(Al + aoff1 + k0n, abn + 12288 + wbB);
            GLD16(Bh + bOff[0] + k0n, bbn + wbB);
            GLD16(Bl + bOff[0] + k0n, bbn + 4096 + wbB);
            LGKM0();
            __builtin_amdgcn_s_setprio(1);
            MFMA_CLUSTER(0, bh0, bl0, bh1, bl1);
            __builtin_amdgcn_s_setprio(0);
            __builtin_amdgcn_sched_barrier(0);
        }

        // -------- phase 1: gate 1; issue b1' --------
        VMCNT(8);
        __builtin_amdgcn_s_barrier();
        {
            bf16x8 bh0 = *(const bf16x8*)(bb + 8192 + boffB[0]);
            bf16x8 bl0 = *(const bf16x8*)(bb + 12288 + boffB[0]);
            bf16x8 bh1 = *(const bf16x8*)(bb + 8192 + boffB[1]);
            bf16x8 bl1 = *(const bf16x8*)(bb + 12288 + boffB[1]);
            GLD16(Bh + bOff[1] + k0n, bbn + 8192 + wbB);
            GLD16(Bl + bOff[1] + k0n, bbn + 12288 + wbB);
            LGKM0();
            __builtin_amdgcn_s_setprio(1);
            MFMA_CLUSTER(1, bh0, bl0, bh1, bl1);
            __builtin_amdgcn_s_setprio(0);
            __builtin_amdgcn_sched_barrier(0);
        }

        // -------- phase 2: gate 2; issue b2' --------
        VMCNT(8);
        __builtin_amdgcn_s_barrier();
        {
            bf16x8 bh0 = *(const bf16x8*)(bb + 16384 + boffB[0]);
            bf16x8 bl0 = *(const bf16x8*)(bb + 20480 + boffB[0]);
            bf16x8 bh1 = *(const bf16x8*)(bb + 16384 + boffB[1]);
            bf16x8 bl1 = *(const bf16x8*)(bb + 20480 + boffB[1]);
            GLD16(Bh + bOff[2] + k0n, bbn + 16384 + wbB);
            GLD16(Bl + bOff[2] + k0n, bbn + 20480 + wbB);
            LGKM0();
            __builtin_amdgcn_s_setprio(1);
            MFMA_CLUSTER(2, bh0, bl0, bh1, bl1);
            __builtin_amdgcn_s_setprio(0);
            __builtin_amdgcn_sched_barrier(0);
        }
    }

    // ---- kt = 23 peeled: no prefetch issues; exact drains 4/2/0 -----------
    {
        const char* ab = smem + 16384;                   // 23&1 == 1
        const char* bb = smem + 32768 + 24576;

        VMCNT(4);
        __builtin_amdgcn_s_barrier();
        READ_A(ab);
        {
            bf16x8 bh0 = *(const bf16x8*)(bb + boffB[0]);
            bf16x8 bl0 = *(const bf16x8*)(bb + 4096 + boffB[0]);
            bf16x8 bh1 = *(const bf16x8*)(bb + boffB[1]);
            bf16x8 bl1 = *(const bf16x8*)(bb + 4096 + boffB[1]);
            LGKM0();
            __builtin_amdgcn_s_setprio(1);
            MFMA_CLUSTER(0, bh0, bl0, bh1, bl1);
            __builtin_amdgcn_s_setprio(0);
            __builtin_amdgcn_sched_barrier(0);
        }

        VMCNT(2);
        __builtin_amdgcn_s_barrier();
        {
            bf16x8 bh0 = *(const bf16x8*)(bb + 8192 + boffB[0]);
            bf16x8 bl0 = *(const bf16x8*)(bb + 12288 + boffB[0]);
            bf16x8 bh1 = *(const bf16x8*)(bb + 8192 + boffB[1]);
            bf16x8 bl1 = *(const bf16x8*)(bb + 12288 + boffB[1]);
            LGKM0();
            __builtin_amdgcn_s_setprio(1);
            MFMA_CLUSTER(1, bh0, bl0, bh1, bl1);
            __builtin_amdgcn_s_setprio(0);
            __builtin_amdgcn_sched_barrier(0);
        }

        VMCNT(0);
        __builtin_amdgcn_s_barrier();
        {
            bf16x8 bh0 = *(const bf16x8*)(bb + 16384 + boffB[0]);
            bf16x8 bl0 = *(const bf16x8*)(bb + 20480 + boffB[0]);
            bf16x8 bh1 = *(const bf16x8*)(bb + 16384 + boffB[1]);
            bf16x8 bl1 = *(const bf16x8*)(bb + 20480 + boffB[1]);
            LGKM0();
            __builtin_amdgcn_s_setprio(1);
            MFMA_CLUSTER(2, bh0, bl0, bh1, bl1);
            __builtin_amdgcn_s_setprio(0);
            __builtin_amdgcn_sched_barrier(0);
        }
    }

    // ---- epilogue: gates -> h -> partial feats ----------------------------
    float bi[2], bg_[2], bo[2];
    #pragma unroll
    for (int f=0; f<2; ++f){
        bi[f]  = bih[jcol[f]]       + bhh[jcol[f]];
        bg_[f] = bih[512 + jcol[f]] + bhh[512 + jcol[f]];
        bo[f]  = bih[768 + jcol[f]] + bhh[768 + jcol[f]];
    }
    float hv[4][2][4];
    #pragma unroll
    for (int fm=0; fm<4; ++fm)
        #pragma unroll
        for (int fn=0; fn<2; ++fn)
            #pragma unroll
            for (int r=0; r<4; ++r){
                float cv = sigm(acc[0][fm][fn][r] + bi[fn]) *
                           tanhf(acc[1][fm][fn][r] + bg_[fn]);
                hv[fm][fn][r] = sigm(acc[2][fm][fn][r] + bo[fn]) * tanhf(cv);
            }

    __syncthreads();   // all tile reads done before LDS reuse
    for (int i2=tid; i2<NT*64; i2+=256){
        int t = i2 >> 6, j = i2 & 63;
        wts[i2] = wtag[t*HIDD + dir*256 + j0 + j];
    }
    float* fq = featsp + (size_t)q * (NTOK*NT);
    #pragma unroll 1
    for (int ph=0; ph<2; ++ph){
        __syncthreads();
        if (wm == ph){
            #pragma unroll
            for (int fm=0; fm<4; ++fm)
                #pragma unroll
                for (int fn=0; fn<2; ++fn)
                    #pragma unroll
                    for (int r=0; r<4; ++r){
                        int mloc = fm*16 + lq*4 + r;        // 0..63
                        int jloc = wn*32 + fn*16 + lm;      // 0..63
                        hbuf[mloc*65 + jloc] = hv[fm][fn][r];
                    }
        }
        __syncthreads();
        const int mrow = tid & 63, grp = tid >> 6;          // 4 groups x 5 tags
        const int tg0 = grp*5;
        float s[5] = {0.f,0.f,0.f,0.f,0.f};
        for (int j=0;j<64;++j){
            float h = hbuf[mrow*65 + j];
            #pragma unroll
            for (int tt=0; tt<5; ++tt)
                s[tt] = fmaf(h, wts[(tg0+tt)*64 + j], s[tt]);
        }
        const int mglob = row0 + ph*64 + mrow;
        #pragma unroll
        for (int tt=0; tt<5; ++tt)
            fq[(size_t)mglob*NT + tg0 + tt] = s[tt];
    }
}

// ---------------------------------------------------------------------------
// fl loader: identical deterministic sum of the 8 partial buffers + btag.
// ---------------------------------------------------------------------------
__device__ __forceinline__ void load_fl(
    const float* __restrict__ featsp, const float* __restrict__ btg,
    float* fl, int c, int tid, int nthr)
{
    const int base = c*(CLEN*NT/4);
    for (int idx=tid; idx<CLEN*NT/4; idx+=nthr){
        float4 s[8];
        #pragma unroll
        for (int p=0; p<8; ++p)
            s[p] = ((const float4*)(featsp + (size_t)p*NTOK*NT))[base+idx];
        float4 v;
        v.x = ((s[0].x+s[1].x)+(s[2].x+s[3].x)) + ((s[4].x+s[5].x)+(s[6].x+s[7].x));
        v.y = ((s[0].y+s[1].y)+(s[2].y+s[3].y)) + ((s[4].y+s[5].y)+(s[6].y+s[7].y));
        v.z = ((s[0].z+s[1].z)+(s[2].z+s[3].z)) + ((s[4].z+s[5].z)+(s[6].z+s[7].z));
        v.w = ((s[0].w+s[1].w)+(s[2].w+s[3].w)) + ((s[4].w+s[5].w)+(s[6].w+s[7].w));
        int t0 = (idx*4) % 20;
        v.x += btg[t0]; v.y += btg[t0+1]; v.z += btg[t0+2]; v.w += btg[t0+3];
        ((float4*)fl)[idx] = v;
    }
}

// ---------------------------------------------------------------------------
// V1: per-chunk max-plus matrix product P_c (20x20). One block per chunk.
// ---------------------------------------------------------------------------
__global__ __launch_bounds__(512) void vit_chunkmat(
    const float* __restrict__ featsp, const float* __restrict__ btag,
    const float* __restrict__ trans, float* __restrict__ Pall)
{
    __shared__ float fl[CLEN*NT];
    __shared__ float Pb[2][NT*NT];
    const int c = blockIdx.x, tid = threadIdx.x;
    load_fl(featsp, btag, fl, c, tid, 512);
    const bool act = tid < NT*NT;
    const int i = tid/20, j = tid - i*20;
    float tr[NT];
    if (act){
        #pragma unroll
        for (int k=0;k<NT;++k) tr[k] = trans[i*NT+k];
        Pb[0][tid] = (i==j) ? 0.f : -1e30f;
    }
    __syncthreads();
    int cur = 0;
    for (int t=0;t<CLEN;++t){
        float m = -3.0e38f;
        if (act){
            #pragma unroll
            for (int k=0;k<NT;++k) m = fmaxf(m, tr[k] + Pb[cur][k*NT+j]);
            m += fl[t*NT+i];
            Pb[cur^1][tid] = m;
        }
        __syncthreads();
        cur ^= 1;
    }
    if (act) Pall[(size_t)c*(NT*NT) + tid] = Pb[cur][tid];
}

// ---------------------------------------------------------------------------
// V2: sequential chunk scan -> fv at chunk starts + terminal argmax/score.
// ---------------------------------------------------------------------------
__global__ __launch_bounds__(128) void vit_scan(
    const float* __restrict__ Pall, const float* __restrict__ trans,
    float* __restrict__ fvstart, float* __restrict__ dout, int* __restrict__ bestws)
{
    __shared__ float Pb[NT*NT];
    __shared__ float fv[NT];
    const int tid = threadIdx.x;
    float4 pn = {0.f,0.f,0.f,0.f};
    if (tid<100) pn = ((const float4*)Pall)[tid];
    if (tid<NT) fv[tid] = (tid==18) ? 0.f : -10000.f;   // START=18
    for (int c=0;c<CHUNKS;++c){
        if (tid<100) ((float4*)Pb)[tid] = pn;
        if (tid<100 && c+1<CHUNKS) pn = ((const float4*)(Pall + (size_t)(c+1)*(NT*NT)))[tid];
        __syncthreads();
        if (tid<NT) fvstart[c*NT+tid] = fv[tid];
        float nf = -3.0e38f;
        if (tid<NT){
            #pragma unroll
            for (int j=0;j<NT;++j) nf = fmaxf(nf, Pb[tid*NT+j] + fv[j]);
        }
        __syncthreads();
        if (tid<NT) fv[tid] = nf;
    }
    __syncthreads();
    if (tid==0){
        float best = -3.0e38f; int bidx = 0;
        for (int j=0;j<NT;++j){
            float tv = fv[j] + trans[19*NT+j];          // STOP row = 19
            if (tv > best){ best = tv; bidx = j; }
        }
        dout[0] = best;
        bestws[0] = bidx;
    }
}

// ---------------------------------------------------------------------------
// V3: exact per-step replay (reference argmax semantics) -> backpointers + H_c
// ---------------------------------------------------------------------------
__global__ __launch_bounds__(128) void vit_replay(
    const float* __restrict__ featsp, const float* __restrict__ btag,
    const float* __restrict__ trans, const float* __restrict__ fvstart,
    unsigned int* __restrict__ bpout, int* __restrict__ Hout)
{
    __shared__ float fl[CLEN*NT];
    __shared__ float fv[NT];
    __shared__ unsigned char bp[CLEN*NT];
    const int c = blockIdx.x, tid = threadIdx.x;
    load_fl(featsp, btag, fl, c, tid, 128);
    float tr[NT];
    if (tid<NT){
        fv[tid] = fvstart[c*NT+tid];
        #pragma unroll
        for (int k=0;k<NT;++k) tr[k] = trans[tid*NT+k];
    }
    __syncthreads();
    for (int t=0;t<CLEN;++t){
        float best = 0.f; int bj = 0;
        if (tid<NT){
            best = tr[0] + fv[0];
            #pragma unroll
            for (int j=1;j<NT;++j){
                float v = tr[j] + fv[j];
                if (v > best){ best = v; bj = j; }      // strict > == first-win
            }
        }
        __syncthreads();
        if (tid<NT){
            fv[tid] = best + fl[t*NT+tid];
            bp[t*NT+tid] = (unsigned char)bj;
        }
        __syncthreads();
    }
    for (int idx=tid; idx<CLEN*NT/4; idx+=128)
        bpout[(size_t)c*(CLEN*NT/4) + idx] = ((unsigned int*)bp)[idx];
    if (tid<NT){
        int m = tid;
        for (int t=CLEN-1;t>=0;--t) m = bp[t*NT+m];
        Hout[c*NT+tid] = m;
    }
}

// ---------------------------------------------------------------------------
// V4: each block walks the composed chunk maps from bestws down to its own
// chunk, then backtracks its chunk and writes the path slice.
// ---------------------------------------------------------------------------
__global__ __launch_bounds__(64) void bt_fill(
    const unsigned int* __restrict__ bpin, const int* __restrict__ Hin,
    const int* __restrict__ bestws, float* __restrict__ dout)
{
    __shared__ int Hl[CHUNKS*NT];
    __shared__ unsigned char bp[CLEN*NT];
    __shared__ float ob[CLEN];
    const int c = blockIdx.x, tid = threadIdx.x;
    for (int idx=tid; idx<CHUNKS*NT; idx+=64) Hl[idx] = Hin[idx];
    for (int idx=tid; idx<CLEN*NT/4; idx+=64)
        ((unsigned int*)bp)[idx] = bpin[(size_t)c*(CLEN*NT/4) + idx];
    __syncthreads();
    if (tid==0){
        int e = bestws[0];
        for (int cc=CHUNKS-1; cc>c; --cc) e = Hl[cc*NT+e];
        for (int t=CLEN-1;t>=0;--t){ ob[t] = (float)e; e = bp[t*NT+e]; }
    }
    __syncthreads();
    for (int idx=tid; idx<CLEN; idx+=64)
        dout[1 + c*CLEN + idx] = ob[idx];
}

// ---------------------------------------------------------------------------
extern "C" void kernel_launch(void* const* d_in, const int* in_sizes, int n_in,
                              void* d_out, int out_size, void* d_ws, size_t ws_size,
                              hipStream_t stream)
{
    const float* x    = (const float*)d_in[0];
    const float* wf   = (const float*)d_in[1];
    const float* bihf = (const float*)d_in[3];
    const float* bhhf = (const float*)d_in[4];
    const float* wb   = (const float*)d_in[5];
    const float* bihb = (const float*)d_in[7];
    const float* bhhb = (const float*)d_in[8];
    const float* wtag = (const float*)d_in[9];
    const float* btag = (const float*)d_in[10];
    const float* trans= (const float*)d_in[11];
    float* out = (float*)d_out;

    char* w = (char*)d_ws;
    ushort_t* Ah = (ushort_t*)w;         w += 25165824;   // 16384*768*2
    ushort_t* Al = (ushort_t*)w;         w += 25165824;
    ushort_t* Bh = (ushort_t*)w;         w += 2359296;    // 1536*768*2
    ushort_t* Bl = (ushort_t*)w;         w += 2359296;
    float* featsp = (float*)w;           w += 10485760;   // 8 * 16384*20 * 4B
    float* Pall  = (float*)w;            w += 204800;     // 128*400*4
    float* fvst  = (float*)w;            w += 10240;      // 128*20*4
    int* Hmap    = (int*)w;              w += 10240;      // 128*20*4
    unsigned int* bp = (unsigned int*)w; w += 327680;     // 16384*20 bytes
    int* best    = (int*)w;

    conv_kernel<<<13440, 256, 0, stream>>>(x, wf, wb, Ah, Al, Bh, Bl);
    gemm_fused<<<1024, 256, 0, stream>>>(Ah, Al, Bh, Bl, bihf, bhhf, bihb, bhhb,
                                         wtag, featsp);
    vit_chunkmat<<<CHUNKS, 512, 0, stream>>>(featsp, btag, trans, Pall);
    vit_scan<<<1, 128, 0, stream>>>(Pall, trans, fvst, out, best);
    vit_replay<<<CHUNKS, 128, 0, stream>>>(featsp, btag, trans, fvst, bp, Hmap);
    bt_fill<<<CHUNKS, 64, 0, stream>>>(bp, Hmap, best, out);
}